// Round 3
// baseline (306.381 us; speedup 1.0000x reference)
//
#include <hip/hip_runtime.h>

#define NP 250000   // P: permutations
#define NN 100000   // N: nodes
#define NE 400000   // E: edges
#define LL 16
#define DD 16

__device__ __forceinline__ float4 fma4(float a, float4 b, float4 c) {
    float4 r;
    r.x = fmaf(a, b.x, c.x);
    r.y = fmaf(a, b.y, c.y);
    r.z = fmaf(a, b.z, c.z);
    r.w = fmaf(a, b.w, c.w);
    return r;
}

__device__ __forceinline__ float4 shfl_xor4(float4 v, int mask) {
    float4 r;
    r.x = __shfl_xor(v.x, mask, 64);
    r.y = __shfl_xor(v.y, mask, 64);
    r.z = __shfl_xor(v.z, mask, 64);
    r.w = __shfl_xor(v.w, mask, 64);
    return r;
}

// wt[l*256 + d*16 + c] = w[d*256 + c*16 + l]; also zero out[] (fused memset).
__global__ void init_kernel(const float* __restrict__ w,
                            float* __restrict__ wt,
                            float* __restrict__ out) {
    int i = blockIdx.x * 256 + threadIdx.x;
    if (i < 4096) {
        int l = i & 15;
        int c = (i >> 4) & 15;
        int d = i >> 8;
        wt[l * 256 + d * 16 + c] = w[i];  // wt index: l*256 + d*16 + c
    }
    if (i < NN * DD) out[i] = 0.f;
}

// One wave processes perms p = gw, gw+nwaves, ...
// lane: l = lane>>2 (row within perm), q = lane&3 (c-quad owned).
// Registers: Wr[g*4+e] = W[d=(q^g)*4+e][c-quad q][l]  (butterfly-matched d order).
__global__ __launch_bounds__(256) void perm_kernel(
    const float* __restrict__ nfeat,     // [N,16]
    const int* __restrict__ efeat_idx,   // [E]
    const int* __restrict__ n_col,       // [M]
    const float* __restrict__ n_val,     // [M]
    const int* __restrict__ e_col,       // [M]
    const float* __restrict__ e_val,     // [M]
    const int* __restrict__ p_row,       // [P]
    const float* __restrict__ p_val,     // [P]
    const float* __restrict__ wt,        // [16*256] transposed weights
    const float* __restrict__ bias,      // [16]
    const float* __restrict__ bond_emb,  // [4,16]
    float* __restrict__ out,             // [N,16] zero-initialized
    int nwaves)
{
    const int lane = threadIdx.x & 63;
    const int gw = blockIdx.x * (blockDim.x >> 6) + (threadIdx.x >> 6);
    const int l = lane >> 2;
    const int q = lane & 3;

    // persistent weight registers, d-order permuted to match shfl_xor butterfly
    float4 Wr[16];
#pragma unroll
    for (int g = 0; g < 4; ++g) {
#pragma unroll
        for (int e = 0; e < 4; ++e) {
            int d = ((q ^ g) << 2) + e;
            Wr[g * 4 + e] = *(const float4*)(wt + l * 256 + d * 16 + q * 4);
        }
    }
    const float bias_lane = bias[lane & 15];

    for (int p = gw; p < NP; p += nwaves) {
        const int m = p * LL + l;
        // independent loads first
        int nc = n_col[m];
        float nv = n_val[m];
        int ec = e_col[m];
        float ev = e_val[m];
        int prow = p_row[p];     // wave-uniform -> scalar load
        float pv = p_val[p];

        int be = efeat_idx[ec];
        float4 nf = *(const float4*)(nfeat + (size_t)nc * DD + q * 4);
        float4 bf = *(const float4*)(bond_emb + be * DD + q * 4);

        float4 xq;               // x[l, d-quad q]
        xq.x = fmaf(nv, nf.x, ev * bf.x);
        xq.y = fmaf(nv, nf.y, ev * bf.y);
        xq.z = fmaf(nv, nf.z, ev * bf.z);
        xq.w = fmaf(nv, nf.w, ev * bf.w);

        // broadcast x across the 4 q-lanes of this row
        float4 xa0 = xq;                   // quad q
        float4 xa1 = shfl_xor4(xq, 1);     // quad q^1
        float4 xa2 = shfl_xor4(xq, 2);     // quad q^2
        float4 xa3 = shfl_xor4(xa1, 2);    // quad q^3

        // partial for c-quad q, row l: 4 independent accumulator chains
        float4 a0, a1, a2, a3;
        a0 = make_float4(0.f, 0.f, 0.f, 0.f);
        a1 = a0; a2 = a0; a3 = a0;
        a0 = fma4(xa0.x, Wr[0], a0);  a0 = fma4(xa0.y, Wr[1], a0);
        a0 = fma4(xa0.z, Wr[2], a0);  a0 = fma4(xa0.w, Wr[3], a0);
        a1 = fma4(xa1.x, Wr[4], a1);  a1 = fma4(xa1.y, Wr[5], a1);
        a1 = fma4(xa1.z, Wr[6], a1);  a1 = fma4(xa1.w, Wr[7], a1);
        a2 = fma4(xa2.x, Wr[8], a2);  a2 = fma4(xa2.y, Wr[9], a2);
        a2 = fma4(xa2.z, Wr[10], a2); a2 = fma4(xa2.w, Wr[11], a2);
        a3 = fma4(xa3.x, Wr[12], a3); a3 = fma4(xa3.y, Wr[13], a3);
        a3 = fma4(xa3.z, Wr[14], a3); a3 = fma4(xa3.w, Wr[15], a3);
        float4 pc;
        pc.x = (a0.x + a1.x) + (a2.x + a3.x);
        pc.y = (a0.y + a1.y) + (a2.y + a3.y);
        pc.z = (a0.z + a1.z) + (a2.z + a3.z);
        pc.w = (a0.w + a1.w) + (a2.w + a3.w);

        // butterfly-reduce over the 16 rows (lane masks 4,8,16,32)
#pragma unroll
        for (int mask = 4; mask <= 32; mask <<= 1) {
            float4 o = shfl_xor4(pc, mask);
            pc.x += o.x; pc.y += o.y; pc.z += o.z; pc.w += o.w;
        }

        // redistribute: lane c (0..15) takes component c&3 of quad c>>2
        int src = lane >> 2;  // lanes 0..3 hold q=0..3
        float s0 = __shfl(pc.x, src, 64);
        float s1 = __shfl(pc.y, src, 64);
        float s2 = __shfl(pc.z, src, 64);
        float s3 = __shfl(pc.w, src, 64);
        int comp = lane & 3;
        float v = (comp == 0) ? s0 : (comp == 1) ? s1 : (comp == 2) ? s2 : s3;
        v = fmaxf(v + bias_lane, 0.f) * pv;

        if (lane < 16) {
            unsafeAtomicAdd(out + (size_t)prow * DD + lane, v);
        }
    }
}

__global__ __launch_bounds__(256) void gate_kernel(
    const float* __restrict__ degs,  // [N]
    const float* __restrict__ W0,    // [1,32]
    const float* __restrict__ b0,    // [32]
    const float* __restrict__ W1,    // [32,16]
    const float* __restrict__ b1,    // [16]
    float* __restrict__ out)         // [N,16] in-place multiply
{
    int n = blockIdx.x * 256 + threadIdx.x;
    if (n >= NN) return;
    float dg = degs[n];

    float4 fd[4];
    fd[0] = ((const float4*)b1)[0];
    fd[1] = ((const float4*)b1)[1];
    fd[2] = ((const float4*)b1)[2];
    fd[3] = ((const float4*)b1)[3];

#pragma unroll
    for (int j = 0; j < 32; ++j) {
        float h = fmaxf(fmaf(dg, W0[j], b0[j]), 0.f);
        const float4* w1r = (const float4*)(W1 + j * 16);
        fd[0] = fma4(h, w1r[0], fd[0]);
        fd[1] = fma4(h, w1r[1], fd[1]);
        fd[2] = fma4(h, w1r[2], fd[2]);
        fd[3] = fma4(h, w1r[3], fd[3]);
    }

    float4* o = (float4*)(out + (size_t)n * DD);
#pragma unroll
    for (int ii = 0; ii < 4; ++ii) {
        float4 v = o[ii];
        v.x *= fd[ii].x;
        v.y *= fd[ii].y;
        v.z *= fd[ii].z;
        v.w *= fd[ii].w;
        o[ii] = v;
    }
}

extern "C" void kernel_launch(void* const* d_in, const int* in_sizes, int n_in,
                              void* d_out, int out_size, void* d_ws, size_t ws_size,
                              hipStream_t stream) {
    const float* nfeat     = (const float*)d_in[0];
    const int*   efeat_idx = (const int*)d_in[1];
    // d_in[2] n_row = arange(M), unused
    const int*   n_col     = (const int*)d_in[3];
    const float* n_val     = (const float*)d_in[4];
    // d_in[5] e_row = arange(M), unused
    const int*   e_col     = (const int*)d_in[6];
    const float* e_val     = (const float*)d_in[7];
    const int*   p_row     = (const int*)d_in[8];
    // d_in[9] p_col = arange(P), unused
    const float* p_val     = (const float*)d_in[10];
    const float* degs      = (const float*)d_in[11];
    const float* weights   = (const float*)d_in[12];
    const float* bias      = (const float*)d_in[13];
    const float* W0        = (const float*)d_in[14];
    const float* b0        = (const float*)d_in[15];
    const float* W1        = (const float*)d_in[16];
    const float* b1        = (const float*)d_in[17];
    const float* bond_emb  = (const float*)d_in[18];

    float* out = (float*)d_out;
    float* wt  = (float*)d_ws;  // 4096 floats

    // zero out[] + transpose weights, one kernel
    init_kernel<<<(NN * DD + 255) / 256, 256, 0, stream>>>(weights, wt, out);

    const int nblocks = 2048;                   // 4 waves each
    const int nwaves = nblocks * 4;
    perm_kernel<<<nblocks, 256, 0, stream>>>(
        nfeat, efeat_idx, n_col, n_val, e_col, e_val, p_row, p_val,
        wt, bias, bond_emb, out, nwaves);
    gate_kernel<<<(NN + 255) / 256, 256, 0, stream>>>(degs, W0, b0, W1, b1, out);
}

// Round 4
// 282.916 us; speedup vs baseline: 1.0829x; 1.0829x over previous
//
#include <hip/hip_runtime.h>

#define NP 250000   // P: permutations
#define NN 100000   // N: nodes
#define NE 400000   // E: edges
#define LL 16
#define DD 16
#define NTILES (NP / 16)   // 15625 exact

typedef __bf16 bf16x8 __attribute__((ext_vector_type(8)));
typedef float f32x4 __attribute__((ext_vector_type(4)));

__device__ __forceinline__ float4 fma4(float a, float4 b, float4 c) {
    float4 r;
    r.x = fmaf(a, b.x, c.x);
    r.y = fmaf(a, b.y, c.y);
    r.z = fmaf(a, b.z, c.z);
    r.w = fmaf(a, b.w, c.w);
    return r;
}

// Build B-fragments of Wf[k=(l*16+d)][c] = weights[d][c][l] in mfma_16x16x32
// fragment order: wfrag[kb*512 + lane*8 + j] = Wf[kb*32 + (lane>>4)*8 + j][lane&15].
// Also zero out[] and (optionally) precompute the degree-gate table fd[N,16].
__global__ __launch_bounds__(256) void init_kernel(
    const float* __restrict__ w,      // [16,16,16] (d,c,l)
    const float* __restrict__ degs,   // [N]
    const float* __restrict__ W0,     // [1,32]
    const float* __restrict__ b0,     // [32]
    const float* __restrict__ W1,     // [32,16]
    const float* __restrict__ b1,     // [16]
    __bf16* __restrict__ wfrag,       // [8*64*8]
    float* __restrict__ fd,           // [N,16] (may be unused)
    float* __restrict__ out,          // [N,16] -> zeroed
    int fuse_fd)
{
    int t = blockIdx.x * 256 + threadIdx.x;
    if (t < 4096) {
        int kb = t >> 9;
        int lane = (t >> 3) & 63;
        int j = t & 7;
        int quad = lane >> 4, c = lane & 15;
        int d = ((quad & 1) << 3) + j;
        int l = (kb << 1) + (quad >> 1);
        wfrag[t] = (__bf16)w[d * 256 + c * 16 + l];
    }
    if (t < NN * DD) out[t] = 0.f;
    if (fuse_fd && t < NN) {
        float dg = degs[t];
        float4 a0 = ((const float4*)b1)[0];
        float4 a1 = ((const float4*)b1)[1];
        float4 a2 = ((const float4*)b1)[2];
        float4 a3 = ((const float4*)b1)[3];
#pragma unroll
        for (int j = 0; j < 32; ++j) {
            float h = fmaxf(fmaf(dg, W0[j], b0[j]), 0.f);
            const float4* w1r = (const float4*)(W1 + j * 16);
            a0 = fma4(h, w1r[0], a0);
            a1 = fma4(h, w1r[1], a1);
            a2 = fma4(h, w1r[2], a2);
            a3 = fma4(h, w1r[3], a3);
        }
        float4* o = (float4*)(fd + (size_t)t * DD);
        o[0] = a0; o[1] = a1; o[2] = a2; o[3] = a3;
    }
}

// One wave per 16-perm tile. A[m=lane&15][k=quad*8+j] (m = perm-in-tile),
// k = l*16+d  ->  lane's slice: l = kb*2 + (quad>>1), d = (quad&1)*8 + j.
// C/D: col=lane&15 (channel), row=quad*4+reg (perm-in-tile).
__global__ __launch_bounds__(256) void perm_kernel(
    const float* __restrict__ nfeat,     // [N,16]
    const int* __restrict__ efeat_idx,   // [E]
    const int* __restrict__ n_col,       // [M]
    const float* __restrict__ n_val,     // [M]
    const int* __restrict__ e_col,       // [M]
    const float* __restrict__ e_val,     // [M]
    const int* __restrict__ p_row,       // [P]
    const float* __restrict__ p_val,     // [P]
    const __bf16* __restrict__ wfrag,    // [8*64*8]
    const float* __restrict__ bias,      // [16]
    const float* __restrict__ bond_emb,  // [4,16]
    const float* __restrict__ fd,        // [N,16] gate table (if fuse_fd)
    float* __restrict__ out,             // [N,16] zero-initialized
    int nwaves, int fuse_fd)
{
    const int lane = threadIdx.x & 63;
    const int wid = blockIdx.x * (blockDim.x >> 6) + (threadIdx.x >> 6);
    const int quad = lane >> 4;
    const int col = lane & 15;
    const int dhalf = (quad & 1) << 3;
    const int lofs = quad >> 1;

    // persistent weight B-fragments (32 VGPRs)
    bf16x8 wf[8];
#pragma unroll
    for (int kb = 0; kb < 8; ++kb)
        wf[kb] = *(const bf16x8*)(wfrag + (kb * 64 + lane) * 8);
    const float bias_c = bias[col];

    for (int tile = wid; tile < NTILES; tile += nwaves) {
        const int pbase = tile * 16;
        const int pm = pbase + col;          // A-row perm for this lane
        f32x4 acc = {0.f, 0.f, 0.f, 0.f};

#pragma unroll
        for (int kb = 0; kb < 8; ++kb) {
            const int l = kb * 2 + lofs;
            const int mi = pm * LL + l;
            int nc = n_col[mi];
            float nv = n_val[mi];
            int ec = e_col[mi];
            float ev = e_val[mi];
            int be = efeat_idx[ec];
            const float4* nf = (const float4*)(nfeat + nc * DD + dhalf);
            const float4* bf = (const float4*)(bond_emb + be * DD + dhalf);
            float4 n0 = nf[0], n1 = nf[1];
            float4 bv0 = bf[0], bv1 = bf[1];
            bf16x8 af;
            af[0] = (__bf16)fmaf(nv, n0.x, ev * bv0.x);
            af[1] = (__bf16)fmaf(nv, n0.y, ev * bv0.y);
            af[2] = (__bf16)fmaf(nv, n0.z, ev * bv0.z);
            af[3] = (__bf16)fmaf(nv, n0.w, ev * bv0.w);
            af[4] = (__bf16)fmaf(nv, n1.x, ev * bv1.x);
            af[5] = (__bf16)fmaf(nv, n1.y, ev * bv1.y);
            af[6] = (__bf16)fmaf(nv, n1.z, ev * bv1.z);
            af[7] = (__bf16)fmaf(nv, n1.w, ev * bv1.w);
            acc = __builtin_amdgcn_mfma_f32_16x16x32_bf16(af, wf[kb], acc, 0, 0, 0);
        }

        const int prow_base = pbase + quad * 4;
#pragma unroll
        for (int r = 0; r < 4; ++r) {
            int pp = prow_base + r;
            int prow = p_row[pp];
            float pv = p_val[pp];
            float v = fmaxf(acc[r] + bias_c, 0.f) * pv;
            if (fuse_fd) v *= fd[(size_t)prow * DD + col];
            unsafeAtomicAdd(out + (size_t)prow * DD + col, v);
        }
    }
}

// Fallback (only if ws_size can't hold the fd table): in-place gate multiply.
__global__ __launch_bounds__(256) void gate_kernel(
    const float* __restrict__ degs,
    const float* __restrict__ W0,
    const float* __restrict__ b0,
    const float* __restrict__ W1,
    const float* __restrict__ b1,
    float* __restrict__ out)
{
    int n = blockIdx.x * 256 + threadIdx.x;
    if (n >= NN) return;
    float dg = degs[n];
    float4 a0 = ((const float4*)b1)[0];
    float4 a1 = ((const float4*)b1)[1];
    float4 a2 = ((const float4*)b1)[2];
    float4 a3 = ((const float4*)b1)[3];
#pragma unroll
    for (int j = 0; j < 32; ++j) {
        float h = fmaxf(fmaf(dg, W0[j], b0[j]), 0.f);
        const float4* w1r = (const float4*)(W1 + j * 16);
        a0 = fma4(h, w1r[0], a0);
        a1 = fma4(h, w1r[1], a1);
        a2 = fma4(h, w1r[2], a2);
        a3 = fma4(h, w1r[3], a3);
    }
    float4* o = (float4*)(out + (size_t)n * DD);
    float4 v0 = o[0], v1 = o[1], v2 = o[2], v3 = o[3];
    v0.x *= a0.x; v0.y *= a0.y; v0.z *= a0.z; v0.w *= a0.w;
    v1.x *= a1.x; v1.y *= a1.y; v1.z *= a1.z; v1.w *= a1.w;
    v2.x *= a2.x; v2.y *= a2.y; v2.z *= a2.z; v2.w *= a2.w;
    v3.x *= a3.x; v3.y *= a3.y; v3.z *= a3.z; v3.w *= a3.w;
    o[0] = v0; o[1] = v1; o[2] = v2; o[3] = v3;
}

extern "C" void kernel_launch(void* const* d_in, const int* in_sizes, int n_in,
                              void* d_out, int out_size, void* d_ws, size_t ws_size,
                              hipStream_t stream) {
    const float* nfeat     = (const float*)d_in[0];
    const int*   efeat_idx = (const int*)d_in[1];
    // d_in[2] n_row = arange(M), unused
    const int*   n_col     = (const int*)d_in[3];
    const float* n_val     = (const float*)d_in[4];
    // d_in[5] e_row = arange(M), unused
    const int*   e_col     = (const int*)d_in[6];
    const float* e_val     = (const float*)d_in[7];
    const int*   p_row     = (const int*)d_in[8];
    // d_in[9] p_col = arange(P), unused
    const float* p_val     = (const float*)d_in[10];
    const float* degs      = (const float*)d_in[11];
    const float* weights   = (const float*)d_in[12];
    const float* bias      = (const float*)d_in[13];
    const float* W0        = (const float*)d_in[14];
    const float* b0        = (const float*)d_in[15];
    const float* W1        = (const float*)d_in[16];
    const float* b1        = (const float*)d_in[17];
    const float* bond_emb  = (const float*)d_in[18];

    float* out = (float*)d_out;

    __bf16* wfrag = (__bf16*)d_ws;                      // 4096 bf16 = 8 KB
    float*  fd    = (float*)((char*)d_ws + 8192);       // NN*16 floats = 6.4 MB
    const size_t need = 8192 + (size_t)NN * DD * sizeof(float);
    const int fuse_fd = (ws_size >= need) ? 1 : 0;

    init_kernel<<<(NN * DD + 255) / 256, 256, 0, stream>>>(
        weights, degs, W0, b0, W1, b1, wfrag, fd, out, fuse_fd);

    const int nblocks = 2048;            // 8192 waves = full residency
    const int nwaves = nblocks * 4;
    perm_kernel<<<nblocks, 256, 0, stream>>>(
        nfeat, efeat_idx, n_col, n_val, e_col, e_val, p_row, p_val,
        wfrag, bias, bond_emb, fd, out, nwaves, fuse_fd);

    if (!fuse_fd) {
        gate_kernel<<<(NN + 255) / 256, 256, 0, stream>>>(degs, W0, b0, W1, b1, out);
    }
}

// Round 5
// 222.918 us; speedup vs baseline: 1.3744x; 1.2692x over previous
//
#include <hip/hip_runtime.h>

#define NP 250000   // P: permutations
#define NN 100000   // N: nodes
#define LL 16
#define DD 16
#define NTILES (NP / 16)   // 15625 exact

typedef __bf16 bf16x8 __attribute__((ext_vector_type(8)));
typedef float f32x4 __attribute__((ext_vector_type(4)));

__device__ __forceinline__ float4 fma4(float a, float4 b, float4 c) {
    float4 r;
    r.x = fmaf(a, b.x, c.x);
    r.y = fmaf(a, b.y, c.y);
    r.z = fmaf(a, b.z, c.z);
    r.w = fmaf(a, b.w, c.w);
    return r;
}

// K-mapping for mfma_16x16x32_bf16, call kb (0..7), lane (quad=lane>>4, c=lane&15):
//   d = 8*(quad&1) + j   (j = 0..7, element within fragment)
//   l = 8*(quad>>1) + kb
// wfrag[kb*512 + lane*8 + j] = weights[d][c][l]  (B-fragment order)
// Also: nfeat -> bf16 table, bond_emb -> bf16 table, zero out.
__global__ __launch_bounds__(256) void init_kernel(
    const float* __restrict__ w,        // [16,16,16] (d,c,l)
    const float* __restrict__ nfeat,    // [N,16]
    const float* __restrict__ bond_emb, // [4,16]
    __bf16* __restrict__ wfrag,         // [8*64*8]
    __bf16* __restrict__ nfeat_bf,      // [N,16]
    __bf16* __restrict__ bond_bf,       // [4,16]
    float* __restrict__ out)            // [N,16] -> zeroed
{
    int t = blockIdx.x * 256 + threadIdx.x;
    if (t < 4096) {
        int kb = t >> 9;
        int lane = (t >> 3) & 63;
        int j = t & 7;
        int quad = lane >> 4, c = lane & 15;
        int d = ((quad & 1) << 3) + j;
        int l = ((quad >> 1) << 3) + kb;
        wfrag[t] = (__bf16)w[d * 256 + c * 16 + l];
    }
    if (t < NN * DD) {
        nfeat_bf[t] = (__bf16)nfeat[t];
        out[t] = 0.f;
    }
    if (t < 64) bond_bf[t] = (__bf16)bond_emb[t];
}

// One wave per 16-perm tile. A[m=col][k=quad*8+j]; lane's rows are the 8
// CONSECUTIVE l = 8*(quad>>1)..+7 of perm pbase+col -> vectorized stream loads.
// C/D: col=lane&15 (channel), row=quad*4+reg (perm-in-tile).
__global__ __launch_bounds__(256) void perm_kernel(
    const __bf16* __restrict__ nfeat_bf, // [N,16] bf16
    const int* __restrict__ efeat_idx,   // [E]
    const int* __restrict__ n_col,       // [M]
    const float* __restrict__ n_val,     // [M]
    const int* __restrict__ e_col,       // [M]
    const float* __restrict__ e_val,     // [M]
    const int* __restrict__ p_row,       // [P]
    const float* __restrict__ p_val,     // [P]
    const __bf16* __restrict__ wfrag,    // [8*64*8]
    const float* __restrict__ bias,      // [16]
    const __bf16* __restrict__ bond_bf,  // [4,16] bf16
    float* __restrict__ out,             // [N,16] zero-initialized
    int nwaves)
{
    const int lane = threadIdx.x & 63;
    const int wid = blockIdx.x * (blockDim.x >> 6) + (threadIdx.x >> 6);
    const int quad = lane >> 4;
    const int col = lane & 15;
    const int half = quad & 1;    // d-half this lane holds
    const int lhalf = quad >> 1;  // l-half this lane covers

    // persistent weight B-fragments (32 VGPRs)
    bf16x8 wf[8];
#pragma unroll
    for (int kb = 0; kb < 8; ++kb)
        wf[kb] = *(const bf16x8*)(wfrag + (kb * 64 + lane) * 8);

    // all 4 bond rows (this lane's d-half) live in registers; select by index
    const bf16x8 bq0 = *(const bf16x8*)(bond_bf + 0 * 16 + half * 8);
    const bf16x8 bq1 = *(const bf16x8*)(bond_bf + 1 * 16 + half * 8);
    const bf16x8 bq2 = *(const bf16x8*)(bond_bf + 2 * 16 + half * 8);
    const bf16x8 bq3 = *(const bf16x8*)(bond_bf + 3 * 16 + half * 8);

    const float bias_c = bias[col];

    for (int tile = wid; tile < NTILES; tile += nwaves) {
        const int pbase = tile * 16;
        const int mbase = (pbase + col) * LL + lhalf * 8;

        // up-front vectorized stream loads (independent)
        int4   nca = *(const int4*)(n_col + mbase);
        int4   ncb = *(const int4*)(n_col + mbase + 4);
        float4 nva = *(const float4*)(n_val + mbase);
        float4 nvb = *(const float4*)(n_val + mbase + 4);
        int4   eca = *(const int4*)(e_col + mbase);
        int4   ecb = *(const int4*)(e_col + mbase + 4);
        float4 eva = *(const float4*)(e_val + mbase);
        float4 evb = *(const float4*)(e_val + mbase + 4);

        int   ncs[8] = {nca.x, nca.y, nca.z, nca.w, ncb.x, ncb.y, ncb.z, ncb.w};
        int   ecs[8] = {eca.x, eca.y, eca.z, eca.w, ecb.x, ecb.y, ecb.z, ecb.w};
        float nvs[8] = {nva.x, nva.y, nva.z, nva.w, nvb.x, nvb.y, nvb.z, nvb.w};
        float evs[8] = {eva.x, eva.y, eva.z, eva.w, evb.x, evb.y, evb.z, evb.w};

        // independent gathers, all issued before first MFMA
        int be[8];
#pragma unroll
        for (int kb = 0; kb < 8; ++kb) be[kb] = efeat_idx[ecs[kb]];

        bf16x8 nfr[8];
#pragma unroll
        for (int kb = 0; kb < 8; ++kb)
            nfr[kb] = *(const bf16x8*)(nfeat_bf + ncs[kb] * DD + half * 8);

        f32x4 acc = {0.f, 0.f, 0.f, 0.f};
#pragma unroll
        for (int kb = 0; kb < 8; ++kb) {
            int b = be[kb];
            bf16x8 blo = (b & 1) ? bq1 : bq0;
            bf16x8 bhi = (b & 1) ? bq3 : bq2;
            bf16x8 bsel = (b & 2) ? bhi : blo;
            float nv = nvs[kb], ev = evs[kb];
            bf16x8 af;
#pragma unroll
            for (int j = 0; j < 8; ++j)
                af[j] = (__bf16)fmaf(nv, (float)nfr[kb][j], ev * (float)bsel[j]);
            acc = __builtin_amdgcn_mfma_f32_16x16x32_bf16(af, wf[kb], acc, 0, 0, 0);
        }

        // epilogue: vectorized p loads; lane commits channel `col` of 4 perms
        int4   pr  = *(const int4*)(p_row + pbase + quad * 4);
        float4 pvv = *(const float4*)(p_val + pbase + quad * 4);
        int   prs[4] = {pr.x, pr.y, pr.z, pr.w};
        float pvs[4] = {pvv.x, pvv.y, pvv.z, pvv.w};
#pragma unroll
        for (int r = 0; r < 4; ++r) {
            float v = fmaxf(acc[r] + bias_c, 0.f) * pvs[r];
            unsafeAtomicAdd(out + (size_t)prs[r] * DD + col, v);
        }
    }
}

__global__ __launch_bounds__(256) void gate_kernel(
    const float* __restrict__ degs,  // [N]
    const float* __restrict__ W0,    // [1,32]
    const float* __restrict__ b0,    // [32]
    const float* __restrict__ W1,    // [32,16]
    const float* __restrict__ b1,    // [16]
    float* __restrict__ out)         // [N,16] in-place multiply
{
    int n = blockIdx.x * 256 + threadIdx.x;
    if (n >= NN) return;
    float dg = degs[n];
    float4 a0 = ((const float4*)b1)[0];
    float4 a1 = ((const float4*)b1)[1];
    float4 a2 = ((const float4*)b1)[2];
    float4 a3 = ((const float4*)b1)[3];
#pragma unroll
    for (int j = 0; j < 32; ++j) {
        float h = fmaxf(fmaf(dg, W0[j], b0[j]), 0.f);
        const float4* w1r = (const float4*)(W1 + j * 16);
        a0 = fma4(h, w1r[0], a0);
        a1 = fma4(h, w1r[1], a1);
        a2 = fma4(h, w1r[2], a2);
        a3 = fma4(h, w1r[3], a3);
    }
    float4* o = (float4*)(out + (size_t)n * DD);
    float4 v0 = o[0], v1 = o[1], v2 = o[2], v3 = o[3];
    v0.x *= a0.x; v0.y *= a0.y; v0.z *= a0.z; v0.w *= a0.w;
    v1.x *= a1.x; v1.y *= a1.y; v1.z *= a1.z; v1.w *= a1.w;
    v2.x *= a2.x; v2.y *= a2.y; v2.z *= a2.z; v2.w *= a2.w;
    v3.x *= a3.x; v3.y *= a3.y; v3.z *= a3.z; v3.w *= a3.w;
    o[0] = v0; o[1] = v1; o[2] = v2; o[3] = v3;
}

extern "C" void kernel_launch(void* const* d_in, const int* in_sizes, int n_in,
                              void* d_out, int out_size, void* d_ws, size_t ws_size,
                              hipStream_t stream) {
    const float* nfeat     = (const float*)d_in[0];
    const int*   efeat_idx = (const int*)d_in[1];
    // d_in[2] n_row = arange(M), unused
    const int*   n_col     = (const int*)d_in[3];
    const float* n_val     = (const float*)d_in[4];
    // d_in[5] e_row = arange(M), unused
    const int*   e_col     = (const int*)d_in[6];
    const float* e_val     = (const float*)d_in[7];
    const int*   p_row     = (const int*)d_in[8];
    // d_in[9] p_col = arange(P), unused
    const float* p_val     = (const float*)d_in[10];
    const float* degs      = (const float*)d_in[11];
    const float* weights   = (const float*)d_in[12];
    const float* bias      = (const float*)d_in[13];
    const float* W0        = (const float*)d_in[14];
    const float* b0        = (const float*)d_in[15];
    const float* W1        = (const float*)d_in[16];
    const float* b1        = (const float*)d_in[17];
    const float* bond_emb  = (const float*)d_in[18];

    float* out = (float*)d_out;

    __bf16* wfrag    = (__bf16*)d_ws;                         // 4096 bf16 = 8 KB
    __bf16* nfeat_bf = (__bf16*)((char*)d_ws + 8192);         // 1.6M bf16 = 3.2 MB
    __bf16* bond_bf  = nfeat_bf + (size_t)NN * DD;            // 64 bf16

    init_kernel<<<(NN * DD + 255) / 256, 256, 0, stream>>>(
        weights, nfeat, bond_emb, wfrag, nfeat_bf, bond_bf, out);

    const int nblocks = 2048;
    const int nwaves = nblocks * 4;
    perm_kernel<<<nblocks, 256, 0, stream>>>(
        nfeat_bf, efeat_idx, n_col, n_val, e_col, e_val, p_row, p_val,
        wfrag, bias, bond_bf, out, nwaves);

    gate_kernel<<<(NN + 255) / 256, 256, 0, stream>>>(degs, W0, b0, W1, b1, out);
}

// Round 6
// 212.314 us; speedup vs baseline: 1.4431x; 1.0499x over previous
//
#include <hip/hip_runtime.h>

#define NP 250000   // P: permutations
#define NN 100000   // N: nodes
#define NE 400000   // E: edges
#define LL 16
#define DD 16
#define MM (NP * LL)        // 4,000,000
#define NTILES (NP / 16)    // 15625 exact

typedef __bf16 bf16x8 __attribute__((ext_vector_type(8)));
typedef float f32x4 __attribute__((ext_vector_type(4)));

__device__ __forceinline__ float4 fma4(float a, float4 b, float4 c) {
    float4 r;
    r.x = fmaf(a, b.x, c.x);
    r.y = fmaf(a, b.y, c.y);
    r.z = fmaf(a, b.z, c.z);
    r.w = fmaf(a, b.w, c.w);
    return r;
}

// K-mapping for mfma_16x16x32_bf16, kb (0..7), lane (quad=lane>>4, c=lane&15):
//   d = 8*(quad&1) + j,  l = 8*(quad>>1) + kb
// wfrag[kb*512 + lane*8 + j] = weights[d][c][l]  (B-fragment order)
// Also: nfeat->bf16 table, bond->bf16, zero out, and be2: 2-bit packed
// bond indices  be2[m>>2] bits (2*(m&3)) = efeat_idx[e_col[m]].
__global__ __launch_bounds__(256) void init_kernel(
    const float* __restrict__ w,          // [16,16,16] (d,c,l)
    const float* __restrict__ nfeat,      // [N,16]
    const float* __restrict__ bond_emb,   // [4,16]
    const int* __restrict__ e_col,        // [M]
    const int* __restrict__ efeat_idx,    // [E]
    __bf16* __restrict__ wfrag,           // [8*64*8]
    __bf16* __restrict__ nfeat_bf,        // [N,16]
    __bf16* __restrict__ bond_bf,         // [4,16]
    unsigned char* __restrict__ be2,      // [M/4]
    float* __restrict__ out)              // [N,16] -> zeroed
{
    int t = blockIdx.x * 256 + threadIdx.x;
    if (t < 4096) {
        int kb = t >> 9;
        int lane = (t >> 3) & 63;
        int j = t & 7;
        int quad = lane >> 4, c = lane & 15;
        int d = ((quad & 1) << 3) + j;
        int l = ((quad >> 1) << 3) + kb;
        wfrag[t] = (__bf16)w[d * 256 + c * 16 + l];
    }
    if (t < NN * DD) {
        nfeat_bf[t] = (__bf16)nfeat[t];
        out[t] = 0.f;
    }
    if (t < 64) bond_bf[t] = (__bf16)bond_emb[t];
    if (t < MM / 4) {
        int4 ec = *(const int4*)(e_col + t * 4);
        unsigned int b0 = (unsigned int)efeat_idx[ec.x] & 3u;
        unsigned int b1 = (unsigned int)efeat_idx[ec.y] & 3u;
        unsigned int b2 = (unsigned int)efeat_idx[ec.z] & 3u;
        unsigned int b3 = (unsigned int)efeat_idx[ec.w] & 3u;
        be2[t] = (unsigned char)(b0 | (b1 << 2) | (b2 << 4) | (b3 << 6));
    }
}

// One wave per 16-perm tile. A[m=col][k=quad*8+j]; lane's rows are the 8
// CONSECUTIVE l = 8*(quad>>1)..+7 of perm pbase+col -> vectorized stream loads.
// C/D: col=lane&15 (channel), row=quad*4+reg (perm-in-tile).
__global__ __launch_bounds__(256) void perm_kernel(
    const __bf16* __restrict__ nfeat_bf,   // [N,16] bf16
    const int* __restrict__ n_col,         // [M]
    const float* __restrict__ n_val,       // [M]
    const float* __restrict__ e_val,       // [M]
    const unsigned char* __restrict__ be2, // [M/4] packed bond indices
    const int* __restrict__ p_row,         // [P]
    const float* __restrict__ p_val,       // [P]
    const __bf16* __restrict__ wfrag,      // [8*64*8]
    const float* __restrict__ bias,        // [16]
    const __bf16* __restrict__ bond_bf,    // [4,16] bf16
    float* __restrict__ out,               // [N,16] zero-initialized
    int nwaves)
{
    const int lane = threadIdx.x & 63;
    const int wid = blockIdx.x * (blockDim.x >> 6) + (threadIdx.x >> 6);
    const int quad = lane >> 4;
    const int col = lane & 15;
    const int half = quad & 1;    // d-half this lane holds
    const int lhalf = quad >> 1;  // l-half this lane covers

    // persistent weight B-fragments (32 VGPRs)
    bf16x8 wf[8];
#pragma unroll
    for (int kb = 0; kb < 8; ++kb)
        wf[kb] = *(const bf16x8*)(wfrag + (kb * 64 + lane) * 8);

    // all 4 bond rows (this lane's d-half) in registers; select by index bits
    const bf16x8 bq0 = *(const bf16x8*)(bond_bf + 0 * 16 + half * 8);
    const bf16x8 bq1 = *(const bf16x8*)(bond_bf + 1 * 16 + half * 8);
    const bf16x8 bq2 = *(const bf16x8*)(bond_bf + 2 * 16 + half * 8);
    const bf16x8 bq3 = *(const bf16x8*)(bond_bf + 3 * 16 + half * 8);

    const float bias_c = bias[col];

    for (int tile = wid; tile < NTILES; tile += nwaves) {
        const int pbase = tile * 16;
        const int mbase = (pbase + col) * LL + lhalf * 8;

        // up-front vectorized stream loads (independent)
        int4   nca = *(const int4*)(n_col + mbase);
        int4   ncb = *(const int4*)(n_col + mbase + 4);
        float4 nva = *(const float4*)(n_val + mbase);
        float4 nvb = *(const float4*)(n_val + mbase + 4);
        float4 eva = *(const float4*)(e_val + mbase);
        float4 evb = *(const float4*)(e_val + mbase + 4);
        unsigned int be16 = *(const unsigned short*)(be2 + (mbase >> 2));

        int   ncs[8] = {nca.x, nca.y, nca.z, nca.w, ncb.x, ncb.y, ncb.z, ncb.w};
        float nvs[8] = {nva.x, nva.y, nva.z, nva.w, nvb.x, nvb.y, nvb.z, nvb.w};
        float evs[8] = {eva.x, eva.y, eva.z, eva.w, evb.x, evb.y, evb.z, evb.w};

        // independent row gathers, all issued before first MFMA
        bf16x8 nfr[8];
#pragma unroll
        for (int kb = 0; kb < 8; ++kb)
            nfr[kb] = *(const bf16x8*)(nfeat_bf + ncs[kb] * DD + half * 8);

        f32x4 acc = {0.f, 0.f, 0.f, 0.f};
#pragma unroll
        for (int kb = 0; kb < 8; ++kb) {
            unsigned int b = (be16 >> (2 * kb)) & 3u;
            bf16x8 blo = (b & 1) ? bq1 : bq0;
            bf16x8 bhi = (b & 1) ? bq3 : bq2;
            bf16x8 bsel = (b & 2) ? bhi : blo;
            float nv = nvs[kb], ev = evs[kb];
            bf16x8 af;
#pragma unroll
            for (int j = 0; j < 8; ++j)
                af[j] = (__bf16)fmaf(nv, (float)nfr[kb][j], ev * (float)bsel[j]);
            acc = __builtin_amdgcn_mfma_f32_16x16x32_bf16(af, wf[kb], acc, 0, 0, 0);
        }

        // epilogue: lane commits channel `col` of its quad's 4 perms
        int4   pr  = *(const int4*)(p_row + pbase + quad * 4);
        float4 pvv = *(const float4*)(p_val + pbase + quad * 4);
        int   prs[4] = {pr.x, pr.y, pr.z, pr.w};
        float pvs[4] = {pvv.x, pvv.y, pvv.z, pvv.w};
#pragma unroll
        for (int r = 0; r < 4; ++r) {
            float v = fmaxf(acc[r] + bias_c, 0.f) * pvs[r];
            unsafeAtomicAdd(out + (size_t)prs[r] * DD + col, v);
        }
    }
}

__global__ __launch_bounds__(256) void gate_kernel(
    const float* __restrict__ degs,  // [N]
    const float* __restrict__ W0,    // [1,32]
    const float* __restrict__ b0,    // [32]
    const float* __restrict__ W1,    // [32,16]
    const float* __restrict__ b1,    // [16]
    float* __restrict__ out)         // [N,16] in-place multiply
{
    int n = blockIdx.x * 256 + threadIdx.x;
    if (n >= NN) return;
    float dg = degs[n];
    float4 a0 = ((const float4*)b1)[0];
    float4 a1 = ((const float4*)b1)[1];
    float4 a2 = ((const float4*)b1)[2];
    float4 a3 = ((const float4*)b1)[3];
#pragma unroll
    for (int j = 0; j < 32; ++j) {
        float h = fmaxf(fmaf(dg, W0[j], b0[j]), 0.f);
        const float4* w1r = (const float4*)(W1 + j * 16);
        a0 = fma4(h, w1r[0], a0);
        a1 = fma4(h, w1r[1], a1);
        a2 = fma4(h, w1r[2], a2);
        a3 = fma4(h, w1r[3], a3);
    }
    float4* o = (float4*)(out + (size_t)n * DD);
    float4 v0 = o[0], v1 = o[1], v2 = o[2], v3 = o[3];
    v0.x *= a0.x; v0.y *= a0.y; v0.z *= a0.z; v0.w *= a0.w;
    v1.x *= a1.x; v1.y *= a1.y; v1.z *= a1.z; v1.w *= a1.w;
    v2.x *= a2.x; v2.y *= a2.y; v2.z *= a2.z; v2.w *= a2.w;
    v3.x *= a3.x; v3.y *= a3.y; v3.z *= a3.z; v3.w *= a3.w;
    o[0] = v0; o[1] = v1; o[2] = v2; o[3] = v3;
}

extern "C" void kernel_launch(void* const* d_in, const int* in_sizes, int n_in,
                              void* d_out, int out_size, void* d_ws, size_t ws_size,
                              hipStream_t stream) {
    const float* nfeat     = (const float*)d_in[0];
    const int*   efeat_idx = (const int*)d_in[1];
    // d_in[2] n_row = arange(M), unused
    const int*   n_col     = (const int*)d_in[3];
    const float* n_val     = (const float*)d_in[4];
    // d_in[5] e_row = arange(M), unused
    const int*   e_col     = (const int*)d_in[6];
    const float* e_val     = (const float*)d_in[7];
    const int*   p_row     = (const int*)d_in[8];
    // d_in[9] p_col = arange(P), unused
    const float* p_val     = (const float*)d_in[10];
    const float* degs      = (const float*)d_in[11];
    const float* weights   = (const float*)d_in[12];
    const float* bias      = (const float*)d_in[13];
    const float* W0        = (const float*)d_in[14];
    const float* b0        = (const float*)d_in[15];
    const float* W1        = (const float*)d_in[16];
    const float* b1        = (const float*)d_in[17];
    const float* bond_emb  = (const float*)d_in[18];

    float* out = (float*)d_out;

    // ws layout (16B-aligned blocks): wfrag 8KB | nfeat_bf 3.2MB | bond 128B | be2 1MB
    char* wsb = (char*)d_ws;
    __bf16*        wfrag    = (__bf16*)wsb;                                // 8192 B
    __bf16*        nfeat_bf = (__bf16*)(wsb + 8192);                       // 3,200,000 B
    __bf16*        bond_bf  = (__bf16*)(wsb + 8192 + 3200000);             // 128 B
    unsigned char* be2      = (unsigned char*)(wsb + 8192 + 3200000 + 128);// 1,000,000 B

    // grid must cover max(NN*DD, MM/4) = 1.6M threads
    init_kernel<<<(NN * DD + 255) / 256, 256, 0, stream>>>(
        weights, nfeat, bond_emb, e_col, efeat_idx,
        wfrag, nfeat_bf, bond_bf, be2, out);

    const int nblocks = 2048;
    const int nwaves = nblocks * 4;
    perm_kernel<<<nblocks, 256, 0, stream>>>(
        nfeat_bf, n_col, n_val, e_val, be2, p_row, p_val,
        wfrag, bias, bond_bf, out, nwaves);

    gate_kernel<<<(NN + 255) / 256, 256, 0, stream>>>(degs, W0, b0, W1, b1, out);
}

// Round 7
// 211.710 us; speedup vs baseline: 1.4472x; 1.0029x over previous
//
#include <hip/hip_runtime.h>

#define NP 250000   // P: permutations
#define NN 100000   // N: nodes
#define NE 400000   // E: edges
#define LL 16
#define DD 16
#define MM (NP * LL)        // 4,000,000
#define NTILES (NP / 16)    // 15625 exact

typedef __bf16 bf16x8 __attribute__((ext_vector_type(8)));
typedef float f32x4 __attribute__((ext_vector_type(4)));

__device__ __forceinline__ float4 fma4(float a, float4 b, float4 c) {
    float4 r;
    r.x = fmaf(a, b.x, c.x);
    r.y = fmaf(a, b.y, c.y);
    r.z = fmaf(a, b.z, c.z);
    r.w = fmaf(a, b.w, c.w);
    return r;
}

// K-mapping for mfma_16x16x32_bf16, kb (0..7), lane (quad=lane>>4, c=lane&15):
//   d = 8*(quad&1) + j,  l = 8*(quad>>1) + kb
// wfrag[kb*512 + lane*8 + j] = weights[d][c][l]  (B-fragment order)
// Also: nfeat->bf16 table, bond->bf16, zero out, and be2: 2-bit packed
// bond indices  be2[m>>2] bits (2*(m&3)) = efeat_idx[e_col[m]].
__global__ __launch_bounds__(256) void init_kernel(
    const float* __restrict__ w,          // [16,16,16] (d,c,l)
    const float* __restrict__ nfeat,      // [N,16]
    const float* __restrict__ bond_emb,   // [4,16]
    const int* __restrict__ e_col,        // [M]
    const int* __restrict__ efeat_idx,    // [E]
    __bf16* __restrict__ wfrag,           // [8*64*8]
    __bf16* __restrict__ nfeat_bf,        // [N,16]
    __bf16* __restrict__ bond_bf,         // [4,16]
    unsigned char* __restrict__ be2,      // [M/4]
    float* __restrict__ out)              // [N,16] -> zeroed
{
    int t = blockIdx.x * 256 + threadIdx.x;
    if (t < 4096) {
        int kb = t >> 9;
        int lane = (t >> 3) & 63;
        int j = t & 7;
        int quad = lane >> 4, c = lane & 15;
        int d = ((quad & 1) << 3) + j;
        int l = ((quad >> 1) << 3) + kb;
        wfrag[t] = (__bf16)w[d * 256 + c * 16 + l];
    }
    if (t < NN * DD) {
        nfeat_bf[t] = (__bf16)nfeat[t];
        out[t] = 0.f;
    }
    if (t < 64) bond_bf[t] = (__bf16)bond_emb[t];
    if (t < MM / 4) {
        int4 ec = *(const int4*)(e_col + t * 4);
        unsigned int b0 = (unsigned int)efeat_idx[ec.x] & 3u;
        unsigned int b1 = (unsigned int)efeat_idx[ec.y] & 3u;
        unsigned int b2 = (unsigned int)efeat_idx[ec.z] & 3u;
        unsigned int b3 = (unsigned int)efeat_idx[ec.w] & 3u;
        be2[t] = (unsigned char)(b0 | (b1 << 2) | (b2 << 4) | (b3 << 6));
    }
}

// ONE 64-thread block (= one wave) per 16-perm tile: fine-grained dispatch,
// no monolithic residency round. A[m=col][k=quad*8+j]; lane's rows are the 8
// CONSECUTIVE l = 8*(quad>>1)..+7 of perm pbase+col.
// C/D: col=lane&15 (channel), row=quad*4+reg (perm-in-tile).
__global__ __launch_bounds__(64) void perm_kernel(
    const __bf16* __restrict__ nfeat_bf,   // [N,16] bf16
    const int* __restrict__ n_col,         // [M]
    const float* __restrict__ n_val,       // [M]
    const float* __restrict__ e_val,       // [M]
    const unsigned char* __restrict__ be2, // [M/4] packed bond indices
    const int* __restrict__ p_row,         // [P]
    const float* __restrict__ p_val,       // [P]
    const __bf16* __restrict__ wfrag,      // [8*64*8]
    const float* __restrict__ bias,        // [16]
    const __bf16* __restrict__ bond_bf,    // [4,16] bf16
    float* __restrict__ out)               // [N,16] zero-initialized
{
    const int lane = threadIdx.x;          // 0..63
    const int tile = blockIdx.x;
    const int quad = lane >> 4;
    const int col = lane & 15;
    const int half = quad & 1;    // d-half this lane holds
    const int lhalf = quad >> 1;  // l-half this lane covers

    const int pbase = tile * 16;
    const int mbase = (pbase + col) * LL + lhalf * 8;

    // issue ALL independent loads up front
    int4   nca = *(const int4*)(n_col + mbase);
    int4   ncb = *(const int4*)(n_col + mbase + 4);
    float4 nva = *(const float4*)(n_val + mbase);
    float4 nvb = *(const float4*)(n_val + mbase + 4);
    float4 eva = *(const float4*)(e_val + mbase);
    float4 evb = *(const float4*)(e_val + mbase + 4);
    unsigned int be16 = *(const unsigned short*)(be2 + (mbase >> 2));
    int4   pr  = *(const int4*)(p_row + pbase + quad * 4);
    float4 pvv = *(const float4*)(p_val + pbase + quad * 4);

    // weight B-fragments + bond rows + bias (L2-hot, 8 KB shared by all blocks)
    bf16x8 wf[8];
#pragma unroll
    for (int kb = 0; kb < 8; ++kb)
        wf[kb] = *(const bf16x8*)(wfrag + (kb * 64 + lane) * 8);
    const bf16x8 bq0 = *(const bf16x8*)(bond_bf + 0 * 16 + half * 8);
    const bf16x8 bq1 = *(const bf16x8*)(bond_bf + 1 * 16 + half * 8);
    const bf16x8 bq2 = *(const bf16x8*)(bond_bf + 2 * 16 + half * 8);
    const bf16x8 bq3 = *(const bf16x8*)(bond_bf + 3 * 16 + half * 8);
    const float bias_c = bias[col];

    int   ncs[8] = {nca.x, nca.y, nca.z, nca.w, ncb.x, ncb.y, ncb.z, ncb.w};
    float nvs[8] = {nva.x, nva.y, nva.z, nva.w, nvb.x, nvb.y, nvb.z, nvb.w};
    float evs[8] = {eva.x, eva.y, eva.z, eva.w, evb.x, evb.y, evb.z, evb.w};

    // independent row gathers, all issued before first MFMA
    bf16x8 nfr[8];
#pragma unroll
    for (int kb = 0; kb < 8; ++kb)
        nfr[kb] = *(const bf16x8*)(nfeat_bf + ncs[kb] * DD + half * 8);

    f32x4 acc = {0.f, 0.f, 0.f, 0.f};
#pragma unroll
    for (int kb = 0; kb < 8; ++kb) {
        unsigned int b = (be16 >> (2 * kb)) & 3u;
        bf16x8 blo = (b & 1) ? bq1 : bq0;
        bf16x8 bhi = (b & 1) ? bq3 : bq2;
        bf16x8 bsel = (b & 2) ? bhi : blo;
        float nv = nvs[kb], ev = evs[kb];
        bf16x8 af;
#pragma unroll
        for (int j = 0; j < 8; ++j)
            af[j] = (__bf16)fmaf(nv, (float)nfr[kb][j], ev * (float)bsel[j]);
        acc = __builtin_amdgcn_mfma_f32_16x16x32_bf16(af, wf[kb], acc, 0, 0, 0);
    }

    // epilogue: lane commits channel `col` of its quad's 4 perms
    int   prs[4] = {pr.x, pr.y, pr.z, pr.w};
    float pvs[4] = {pvv.x, pvv.y, pvv.z, pvv.w};
#pragma unroll
    for (int r = 0; r < 4; ++r) {
        float v = fmaxf(acc[r] + bias_c, 0.f) * pvs[r];
        unsafeAtomicAdd(out + (size_t)prs[r] * DD + col, v);
    }
}

__global__ __launch_bounds__(256) void gate_kernel(
    const float* __restrict__ degs,  // [N]
    const float* __restrict__ W0,    // [1,32]
    const float* __restrict__ b0,    // [32]
    const float* __restrict__ W1,    // [32,16]
    const float* __restrict__ b1,    // [16]
    float* __restrict__ out)         // [N,16] in-place multiply
{
    int n = blockIdx.x * 256 + threadIdx.x;
    if (n >= NN) return;
    float dg = degs[n];
    float4 a0 = ((const float4*)b1)[0];
    float4 a1 = ((const float4*)b1)[1];
    float4 a2 = ((const float4*)b1)[2];
    float4 a3 = ((const float4*)b1)[3];
#pragma unroll
    for (int j = 0; j < 32; ++j) {
        float h = fmaxf(fmaf(dg, W0[j], b0[j]), 0.f);
        const float4* w1r = (const float4*)(W1 + j * 16);
        a0 = fma4(h, w1r[0], a0);
        a1 = fma4(h, w1r[1], a1);
        a2 = fma4(h, w1r[2], a2);
        a3 = fma4(h, w1r[3], a3);
    }
    float4* o = (float4*)(out + (size_t)n * DD);
    float4 v0 = o[0], v1 = o[1], v2 = o[2], v3 = o[3];
    v0.x *= a0.x; v0.y *= a0.y; v0.z *= a0.z; v0.w *= a0.w;
    v1.x *= a1.x; v1.y *= a1.y; v1.z *= a1.z; v1.w *= a1.w;
    v2.x *= a2.x; v2.y *= a2.y; v2.z *= a2.z; v2.w *= a2.w;
    v3.x *= a3.x; v3.y *= a3.y; v3.z *= a3.z; v3.w *= a3.w;
    o[0] = v0; o[1] = v1; o[2] = v2; o[3] = v3;
}

extern "C" void kernel_launch(void* const* d_in, const int* in_sizes, int n_in,
                              void* d_out, int out_size, void* d_ws, size_t ws_size,
                              hipStream_t stream) {
    const float* nfeat     = (const float*)d_in[0];
    const int*   efeat_idx = (const int*)d_in[1];
    // d_in[2] n_row = arange(M), unused
    const int*   n_col     = (const int*)d_in[3];
    const float* n_val     = (const float*)d_in[4];
    // d_in[5] e_row = arange(M), unused
    const int*   e_col     = (const int*)d_in[6];
    const float* e_val     = (const float*)d_in[7];
    const int*   p_row     = (const int*)d_in[8];
    // d_in[9] p_col = arange(P), unused
    const float* p_val     = (const float*)d_in[10];
    const float* degs      = (const float*)d_in[11];
    const float* weights   = (const float*)d_in[12];
    const float* bias      = (const float*)d_in[13];
    const float* W0        = (const float*)d_in[14];
    const float* b0        = (const float*)d_in[15];
    const float* W1        = (const float*)d_in[16];
    const float* b1        = (const float*)d_in[17];
    const float* bond_emb  = (const float*)d_in[18];

    float* out = (float*)d_out;

    // ws layout (16B-aligned blocks): wfrag 8KB | nfeat_bf 3.2MB | bond 128B | be2 1MB
    char* wsb = (char*)d_ws;
    __bf16*        wfrag    = (__bf16*)wsb;                                // 8192 B
    __bf16*        nfeat_bf = (__bf16*)(wsb + 8192);                       // 3,200,000 B
    __bf16*        bond_bf  = (__bf16*)(wsb + 8192 + 3200000);             // 128 B
    unsigned char* be2      = (unsigned char*)(wsb + 8192 + 3200000 + 128);// 1,000,000 B

    // grid must cover max(NN*DD, MM/4) = 1.6M threads
    init_kernel<<<(NN * DD + 255) / 256, 256, 0, stream>>>(
        weights, nfeat, bond_emb, e_col, efeat_idx,
        wfrag, nfeat_bf, bond_bf, be2, out);

    // one 1-wave block per tile: fine-grained scheduling, no residency cliff
    perm_kernel<<<NTILES, 64, 0, stream>>>(
        nfeat_bf, n_col, n_val, e_val, be2, p_row, p_val,
        wfrag, bias, bond_bf, out);

    gate_kernel<<<(NN + 255) / 256, 256, 0, stream>>>(degs, W0, b0, W1, b1, out);
}